// Round 1
// baseline (5176.401 us; speedup 1.0000x reference)
//
#include <hip/hip_runtime.h>
#include <math.h>

#define NN 50000
#define NE 400000
#define CD 128

__device__ __forceinline__ float silu_f(float z) {
    return z / (1.f + __expf(-z));
}

// ---------------------------------------------------------------------------
// Precompute per-layer: Aep[64][512] = We2 @ [Wn1_ea | Wc1_ea],
//                       cep[512]    = be2 @ [Wn1_ea | Wc1_ea] + [bn1 | bc1]
// grid (65, 4): blockIdx.x = i (row, 64==bias), blockIdx.y = layer
// ---------------------------------------------------------------------------
__global__ __launch_bounds__(512) void prep_kernel(
        const float* __restrict__ We2, const float* __restrict__ be2,
        const float* __restrict__ Wn1, const float* __restrict__ Wc1,
        const float* __restrict__ bn1, const float* __restrict__ bc1,
        float* __restrict__ Aep, float* __restrict__ cep)
{
    const int l = blockIdx.y;
    const int i = blockIdx.x;
    const int j = threadIdx.x;              // 0..511
    const int jj = j & 255;
    const float* W1 = ((j < 256) ? Wn1 : Wc1) + (size_t)l * 320 * 256;
    if (i < 64) {
        const float* We2l = We2 + (size_t)l * 64 * 64;
        float acc = 0.f;
        #pragma unroll 8
        for (int k = 0; k < 64; ++k)
            acc += We2l[i * 64 + k] * W1[(256 + k) * 256 + jj];
        Aep[((size_t)l * 64 + i) * 512 + j] = acc;
    } else {
        const float* be2l = be2 + l * 64;
        float acc = (j < 256) ? bn1[l * 256 + jj] : bc1[l * 256 + jj];
        #pragma unroll 8
        for (int k = 0; k < 64; ++k)
            acc += be2l[k] * W1[(256 + k) * 256 + jj];
        cep[l * 512 + j] = acc;
    }
}

// ---------------------------------------------------------------------------
// Node projection: P[n][0:256]   = h[n] @ Wn1[0:128]     (src part, node MLP)
//                  P[n][256:512] = h[n] @ Wc1[0:128]     (src part, coord MLP)
//                  P[n][512:768] = h[n] @ Wn1[128:256]   (dst part, node MLP)
//                  P[n][768:1024]= h[n] @ Wc1[128:256]   (dst part, coord MLP)
// 16 nodes per block of 256 threads. 50000 = 16*3125 exactly.
// ---------------------------------------------------------------------------
__global__ __launch_bounds__(256) void node_proj_kernel(
        const float* __restrict__ h,
        const float* __restrict__ Wn1l, const float* __restrict__ Wc1l,
        float* __restrict__ P)
{
    __shared__ __align__(16) float hsT[128][20];   // transposed, padded
    const int tid = threadIdx.x;
    const int nb = blockIdx.x * 16;
    for (int idx = tid; idx < 2048; idx += 256) {
        int n = idx >> 7, k = idx & 127;
        hsT[k][n] = h[(size_t)(nb + n) * CD + k];
    }
    __syncthreads();
    #pragma unroll
    for (int cc = 0; cc < 4; ++cc) {
        const float* W = (cc == 0) ? Wn1l
                       : (cc == 1) ? Wc1l
                       : (cc == 2) ? (Wn1l + 128 * 256)
                                   : (Wc1l + 128 * 256);
        float acc[16];
        #pragma unroll
        for (int n = 0; n < 16; ++n) acc[n] = 0.f;
        for (int k = 0; k < 128; ++k) {
            float w = W[(size_t)k * 256 + tid];
            const float4* hp = reinterpret_cast<const float4*>(&hsT[k][0]);
            float4 a0 = hp[0], a1 = hp[1], a2 = hp[2], a3 = hp[3];
            acc[0]  += a0.x * w; acc[1]  += a0.y * w; acc[2]  += a0.z * w; acc[3]  += a0.w * w;
            acc[4]  += a1.x * w; acc[5]  += a1.y * w; acc[6]  += a1.z * w; acc[7]  += a1.w * w;
            acc[8]  += a2.x * w; acc[9]  += a2.y * w; acc[10] += a2.z * w; acc[11] += a2.w * w;
            acc[12] += a3.x * w; acc[13] += a3.y * w; acc[14] += a3.z * w; acc[15] += a3.w * w;
        }
        const int col = cc * 256 + tid;
        #pragma unroll
        for (int n = 0; n < 16; ++n)
            P[(size_t)(nb + n) * 1024 + col] = acc[n];
    }
}

// ---------------------------------------------------------------------------
// Edge phase: 16 edges per block of 256 threads. 400000 = 16*25000 exactly.
//  pre[j] = P[src][j] + P[dst][512+j] + (s @ Aep)[j] + cep[j]   (j in [0,512))
//  t = silu(pre); m = t[0:256]@Wn2 + bn2 -> atomic into h_out[dst]
//  cw = t[256:512].Wc2 -> atomic cw*(x[src]-x[dst]) into x_out[dst]
// ---------------------------------------------------------------------------
__global__ __launch_bounds__(256) void edge_kernel(
        const int* __restrict__ eidx, const float* __restrict__ edist,
        const float* __restrict__ We1l, const float* __restrict__ be1l,
        const float* __restrict__ Aep, const float* __restrict__ cep,
        const float* __restrict__ P,
        const float* __restrict__ Wn2l, const float* __restrict__ bn2l,
        const float* __restrict__ Wc2l,
        const float* __restrict__ x_in,
        float* __restrict__ h_out, float* __restrict__ x_out)
{
    __shared__ __align__(16) float s_sT[64][20];    // silu(d*We1+be1), transposed
    __shared__ __align__(16) float s_tT[512][20];   // hidden t, transposed [col][edge]
    __shared__ int s_src[16], s_dst[16];

    const int tid = threadIdx.x;
    const int eb = blockIdx.x * 16;

    if (tid < 16) {
        s_src[tid] = eidx[eb + tid];
        s_dst[tid] = eidx[NE + eb + tid];
    }
    for (int idx = tid; idx < 1024; idx += 256) {
        int j = idx >> 4, e = idx & 15;
        float d = edist[eb + e];
        s_sT[j][e] = silu_f(d * We1l[j] + be1l[j]);
    }
    __syncthreads();

    int srcs[16], dsts[16];
    #pragma unroll
    for (int e = 0; e < 16; ++e) { srcs[e] = s_src[e]; dsts[e] = s_dst[e]; }

    // ---- phase 2: ep GEMM + gather + silu -> t
    #pragma unroll
    for (int half = 0; half < 2; ++half) {
        const int col = half * 256 + tid;
        float acc[16];
        #pragma unroll
        for (int e = 0; e < 16; ++e) acc[e] = 0.f;
        for (int i = 0; i < 64; ++i) {
            float a = Aep[(size_t)i * 512 + col];
            const float4* sp = reinterpret_cast<const float4*>(&s_sT[i][0]);
            float4 s0 = sp[0], s1 = sp[1], s2 = sp[2], s3 = sp[3];
            acc[0]  += s0.x * a; acc[1]  += s0.y * a; acc[2]  += s0.z * a; acc[3]  += s0.w * a;
            acc[4]  += s1.x * a; acc[5]  += s1.y * a; acc[6]  += s1.z * a; acc[7]  += s1.w * a;
            acc[8]  += s2.x * a; acc[9]  += s2.y * a; acc[10] += s2.z * a; acc[11] += s2.w * a;
            acc[12] += s3.x * a; acc[13] += s3.y * a; acc[14] += s3.z * a; acc[15] += s3.w * a;
        }
        const float base = cep[col];
        float tv[16];
        #pragma unroll
        for (int e = 0; e < 16; ++e) {
            float pre = acc[e] + base
                      + P[(size_t)srcs[e] * 1024 + col]
                      + P[(size_t)dsts[e] * 1024 + 512 + col];
            tv[e] = silu_f(pre);
        }
        float4* tp = reinterpret_cast<float4*>(&s_tT[col][0]);
        tp[0] = make_float4(tv[0],  tv[1],  tv[2],  tv[3]);
        tp[1] = make_float4(tv[4],  tv[5],  tv[6],  tv[7]);
        tp[2] = make_float4(tv[8],  tv[9],  tv[10], tv[11]);
        tp[3] = make_float4(tv[12], tv[13], tv[14], tv[15]);
    }
    __syncthreads();

    // ---- phase 3: m = t[0:256] @ Wn2 + bn2, scatter to h_out
    {
        const int g = tid >> 7;          // edge group 0: edges 0..7, 1: edges 8..15
        const int c = tid & 127;         // output channel
        const int g8 = g * 8;
        float acc2[8];
        #pragma unroll
        for (int e = 0; e < 8; ++e) acc2[e] = 0.f;
        for (int k = 0; k < 256; ++k) {
            float wv = Wn2l[(size_t)k * 128 + c];
            const float4* tp = reinterpret_cast<const float4*>(&s_tT[k][g8]);
            float4 t0 = tp[0], t1 = tp[1];
            acc2[0] += t0.x * wv; acc2[1] += t0.y * wv; acc2[2] += t0.z * wv; acc2[3] += t0.w * wv;
            acc2[4] += t1.x * wv; acc2[5] += t1.y * wv; acc2[6] += t1.z * wv; acc2[7] += t1.w * wv;
        }
        const float bb = bn2l[c];
        #pragma unroll
        for (int e8 = 0; e8 < 8; ++e8) {
            int dn = s_dst[g8 + e8];
            atomicAdd(&h_out[(size_t)dn * CD + c], acc2[e8] + bb);
        }
    }

    // ---- phase 3b: cw = t[256:512].Wc2, coordinate scatter
    {
        const int e = tid >> 4;          // 16 threads per edge
        const int r = tid & 15;
        float part = 0.f;
        #pragma unroll 4
        for (int k = r; k < 256; k += 16)
            part += s_tT[256 + k][e] * Wc2l[k];
        part += __shfl_xor(part, 1);
        part += __shfl_xor(part, 2);
        part += __shfl_xor(part, 4);
        part += __shfl_xor(part, 8);
        if (r == 0) {
            int sn = s_src[e], dn = s_dst[e];
            float cw = part;
            float dx0 = x_in[sn * 3 + 0] - x_in[dn * 3 + 0];
            float dx1 = x_in[sn * 3 + 1] - x_in[dn * 3 + 1];
            float dx2 = x_in[sn * 3 + 2] - x_in[dn * 3 + 2];
            atomicAdd(&x_out[dn * 3 + 0], cw * dx0);
            atomicAdd(&x_out[dn * 3 + 1], cw * dx1);
            atomicAdd(&x_out[dn * 3 + 2], cw * dx2);
        }
    }
}

// ---------------------------------------------------------------------------
// Final LayerNorm over C=128 + copy x. One wave per node, 4 nodes per block.
// ---------------------------------------------------------------------------
__global__ __launch_bounds__(256) void final_kernel(
        const float* __restrict__ h, const float* __restrict__ x,
        const float* __restrict__ gamma, const float* __restrict__ beta,
        float* __restrict__ out)
{
    const int lane = threadIdx.x & 63;
    const int wave = threadIdx.x >> 6;
    const int n = blockIdx.x * 4 + wave;
    float v0 = h[(size_t)n * CD + lane];
    float v1 = h[(size_t)n * CD + 64 + lane];
    float ssum = v0 + v1;
    for (int off = 32; off; off >>= 1) ssum += __shfl_xor(ssum, off);
    float mu = ssum * (1.f / 128.f);
    float d0 = v0 - mu, d1 = v1 - mu;
    float sq = d0 * d0 + d1 * d1;
    for (int off = 32; off; off >>= 1) sq += __shfl_xor(sq, off);
    float rstd = rsqrtf(sq * (1.f / 128.f) + 1e-5f);
    out[(size_t)n * CD + lane]      = gamma[lane]      * d0 * rstd + beta[lane];
    out[(size_t)n * CD + 64 + lane] = gamma[64 + lane] * d1 * rstd + beta[64 + lane];
    if (threadIdx.x < 12) {
        int nn = blockIdx.x * 4 + threadIdx.x / 3;
        int c = threadIdx.x % 3;
        out[(size_t)NN * CD + nn * 3 + c] = x[nn * 3 + c];
    }
}

static inline size_t align_up(size_t v) { return (v + 255) & ~(size_t)255; }

extern "C" void kernel_launch(void* const* d_in, const int* in_sizes, int n_in,
                              void* d_out, int out_size, void* d_ws, size_t ws_size,
                              hipStream_t stream)
{
    const float* single = (const float*)d_in[0];
    const float* coords = (const float*)d_in[2];
    const int*   eidx   = (const int*)d_in[3];
    const float* edist  = (const float*)d_in[4];
    const float* We1 = (const float*)d_in[5];
    const float* be1 = (const float*)d_in[6];
    const float* We2 = (const float*)d_in[7];
    const float* be2 = (const float*)d_in[8];
    const float* Wn1 = (const float*)d_in[9];
    const float* bn1 = (const float*)d_in[10];
    const float* Wn2 = (const float*)d_in[11];
    const float* bn2 = (const float*)d_in[12];
    const float* Wc1 = (const float*)d_in[13];
    const float* bc1 = (const float*)d_in[14];
    const float* Wc2 = (const float*)d_in[15];
    const float* gamma = (const float*)d_in[16];
    const float* beta  = (const float*)d_in[17];
    float* out = (float*)d_out;

    char* w = (char*)d_ws;
    float* P   = (float*)w;  w += align_up((size_t)NN * 1024 * 4);
    float* h0  = (float*)w;  w += align_up((size_t)NN * CD * 4);
    float* h1  = (float*)w;  w += align_up((size_t)NN * CD * 4);
    float* x0  = (float*)w;  w += align_up((size_t)NN * 3 * 4);
    float* x1  = (float*)w;  w += align_up((size_t)NN * 3 * 4);
    float* Aep = (float*)w;  w += align_up((size_t)4 * 64 * 512 * 4);
    float* cep = (float*)w;  w += align_up((size_t)4 * 512 * 4);

    hipMemcpyAsync(h0, single, (size_t)NN * CD * 4, hipMemcpyDeviceToDevice, stream);
    hipMemcpyAsync(x0, coords, (size_t)NN * 3 * 4, hipMemcpyDeviceToDevice, stream);
    prep_kernel<<<dim3(65, 4), 512, 0, stream>>>(We2, be2, Wn1, Wc1, bn1, bc1, Aep, cep);

    float* hc = h0; float* hn = h1; float* xc = x0; float* xn = x1;
    for (int l = 0; l < 4; ++l) {
        node_proj_kernel<<<3125, 256, 0, stream>>>(
            hc, Wn1 + (size_t)l * 320 * 256, Wc1 + (size_t)l * 320 * 256, P);
        hipMemcpyAsync(hn, hc, (size_t)NN * CD * 4, hipMemcpyDeviceToDevice, stream);
        hipMemcpyAsync(xn, xc, (size_t)NN * 3 * 4, hipMemcpyDeviceToDevice, stream);
        edge_kernel<<<25000, 256, 0, stream>>>(
            eidx, edist,
            We1 + l * 64, be1 + l * 64,
            Aep + (size_t)l * 64 * 512, cep + l * 512, P,
            Wn2 + (size_t)l * 256 * 128, bn2 + l * 128, Wc2 + l * 256,
            xc, hn, xn);
        float* t;
        t = hc; hc = hn; hn = t;
        t = xc; xc = xn; xn = t;
    }
    final_kernel<<<12500, 256, 0, stream>>>(hc, xc, gamma, beta, out);
}

// Round 2
// 2452.037 us; speedup vs baseline: 2.1111x; 2.1111x over previous
//
#include <hip/hip_runtime.h>
#include <math.h>

#define NN 50000
#define NE 400000
#define CD 128
#define EPB 32          // edges per block in edge_kernel

typedef __attribute__((ext_vector_type(8))) short bf16x8;
typedef __attribute__((ext_vector_type(4))) float f32x4;

__device__ __forceinline__ float silu_f(float z) {
    return z / (1.f + __expf(-z));
}
__device__ __forceinline__ unsigned short f2bf(float x) {
    unsigned int u = __float_as_uint(x);
    u = (u + 0x7FFFu + ((u >> 16) & 1u)) >> 16;
    return (unsigned short)u;
}
__device__ __forceinline__ float bf2f(unsigned short h) {
    return __uint_as_float(((unsigned int)h) << 16);
}

// ---------------------------------------------------------------------------
// Wbig swizzle prep: Wbig[k][n], k in [0,320), n in [0,512)
//   k<256:  n<256 -> Wn1l[k][n], else Wc1l[k][n-256]
//   k>=256: Aep fold: sum_j We2l[k-256][j] * W1[(256+j)][n']
// Stored in MFMA B-frag lane order: [layer][ntile(32)][kstep(10)][lane(64)][j(8)]
// ---------------------------------------------------------------------------
__global__ __launch_bounds__(64) void wbig_prep(
        const float* __restrict__ We2, const float* __restrict__ Wn1,
        const float* __restrict__ Wc1, unsigned short* __restrict__ wbig)
{
    const int l = blockIdx.y;
    const int ntile = blockIdx.x / 10;
    const int ks = blockIdx.x % 10;
    const int lane = threadIdx.x;
    const int n = ntile * 16 + (lane & 15);
    const int kbase = ks * 32 + (lane >> 4) * 8;
    const float* Wn1l = Wn1 + (size_t)l * 320 * 256;
    const float* Wc1l = Wc1 + (size_t)l * 320 * 256;
    const float* We2l = We2 + (size_t)l * 64 * 64;
    const float* W1 = (n < 256) ? Wn1l : Wc1l;
    const int nn = n & 255;
    unsigned short* outp = wbig + ((((size_t)l * 32 + ntile) * 10 + ks) * 64 + lane) * 8;
    #pragma unroll
    for (int j = 0; j < 8; ++j) {
        int k = kbase + j;
        float val;
        if (k < 256) {
            val = W1[(size_t)k * 256 + nn];
        } else {
            int i = k - 256;
            float acc = 0.f;
            #pragma unroll 8
            for (int jj = 0; jj < 64; ++jj)
                acc += We2l[i * 64 + jj] * W1[(size_t)(256 + jj) * 256 + nn];
            val = acc;
        }
        outp[j] = f2bf(val);
    }
}

// ---------------------------------------------------------------------------
// Wn2 swizzle: B[k][n] = Wn2l[k][n], k in [0,256), n in [0,128)
// [layer][ntile(8)][kstep(8)][lane(64)][j(8)]
// ---------------------------------------------------------------------------
__global__ __launch_bounds__(64) void wn2_prep(
        const float* __restrict__ Wn2, unsigned short* __restrict__ wn2s)
{
    const int l = blockIdx.y;
    const int ntile = blockIdx.x / 8;
    const int ks = blockIdx.x % 8;
    const int lane = threadIdx.x;
    const int n = ntile * 16 + (lane & 15);
    const int kbase = ks * 32 + (lane >> 4) * 8;
    const float* Wn2l = Wn2 + (size_t)l * 256 * 128;
    unsigned short* outp = wn2s + ((((size_t)l * 8 + ntile) * 8 + ks) * 64 + lane) * 8;
    #pragma unroll
    for (int j = 0; j < 8; ++j)
        outp[j] = f2bf(Wn2l[(size_t)(kbase + j) * 128 + n]);
}

// ---------------------------------------------------------------------------
// cep[l][n] = sum_j be2[j]*W1[(256+j)][n'] + bias1[n']   (fp32)
// ---------------------------------------------------------------------------
__global__ __launch_bounds__(512) void cep_prep(
        const float* __restrict__ be2,
        const float* __restrict__ Wn1, const float* __restrict__ Wc1,
        const float* __restrict__ bn1, const float* __restrict__ bc1,
        float* __restrict__ cep)
{
    const int l = blockIdx.x;
    const int j = threadIdx.x;
    const int jj = j & 255;
    const float* W1 = ((j < 256) ? Wn1 : Wc1) + (size_t)l * 320 * 256;
    const float* be2l = be2 + l * 64;
    float acc = (j < 256) ? bn1[l * 256 + jj] : bc1[l * 256 + jj];
    #pragma unroll 8
    for (int k = 0; k < 64; ++k)
        acc += be2l[k] * W1[(size_t)(256 + k) * 256 + jj];
    cep[l * 512 + j] = acc;
}

// ---------------------------------------------------------------------------
// fp32 -> bf16 convert (h shadow), 4 elems/thread
// ---------------------------------------------------------------------------
__global__ __launch_bounds__(256) void conv_kernel(
        const float* __restrict__ h, unsigned short* __restrict__ hbf)
{
    const int i = (blockIdx.x * 256 + threadIdx.x) * 4;
    float4 v = *(const float4*)(h + i);
    ushort4 o;
    o.x = f2bf(v.x); o.y = f2bf(v.y); o.z = f2bf(v.z); o.w = f2bf(v.w);
    *(ushort4*)(hbf + i) = o;
}

// ---------------------------------------------------------------------------
// Fused edge kernel, MFMA. 32 edges/block, 256 threads (4 waves).
// GEMM1: A=[hbf[src]|hbf[dst]|s] (32x320) @ Wbig (320x512) -> silu -> t (LDS)
// GEMM2: t[:,0:256] @ Wn2 (256x128) -> + bn2 -> atomic h_out[dst]
// coord: dot(t[:,256:512], Wc2) -> atomic x_out[dst] += cw*(x[src]-x[dst])
// ---------------------------------------------------------------------------
__global__ __launch_bounds__(256) void edge_kernel(
        const int* __restrict__ eidx, const float* __restrict__ edist,
        const float* __restrict__ We1l, const float* __restrict__ be1l,
        const unsigned short* __restrict__ hbf,
        const unsigned short* __restrict__ wbig_l,
        const unsigned short* __restrict__ wn2_l,
        const float* __restrict__ cep_l, const float* __restrict__ bn2l,
        const float* __restrict__ Wc2l,
        const float* __restrict__ x_in,
        float* __restrict__ h_out, float* __restrict__ x_out)
{
    __shared__ __align__(16) unsigned short s_s[EPB][72];   // s bf16 (64 + 8 pad)
    __shared__ __align__(16) unsigned short s_t[EPB][520];  // t bf16 (512 + 8 pad)
    __shared__ int s_src[EPB], s_dst[EPB];
    __shared__ float s_wc2[256];

    const int tid = threadIdx.x;
    const int eb = blockIdx.x * EPB;

    if (tid < EPB) {
        s_src[tid] = eidx[eb + tid];
        s_dst[tid] = eidx[NE + eb + tid];
    }
    s_wc2[tid] = Wc2l[tid];
    {   // s = silu(d * We1 + be1), 8 elems/thread
        const int e = tid >> 3;
        const int j0 = (tid & 7) * 8;
        const float d = edist[eb + e];
        unsigned short tmp[8];
        #pragma unroll
        for (int j = 0; j < 8; ++j)
            tmp[j] = f2bf(silu_f(d * We1l[j0 + j] + be1l[j0 + j]));
        *(bf16x8*)&s_s[e][j0] = *(const bf16x8*)tmp;
    }
    __syncthreads();

    const int wave = tid >> 6, lane = tid & 63;
    const int m = lane & 15, q = lane >> 4;
    const int e0 = m, e1 = 16 + m;
    const int src0 = s_src[e0], src1 = s_src[e1];
    const int dst0 = s_dst[e0], dst1 = s_dst[e1];

    // ---- GEMM1 ----
    f32x4 acc[8][2];
    #pragma unroll
    for (int nt = 0; nt < 8; ++nt) {
        acc[nt][0] = (f32x4){0.f, 0.f, 0.f, 0.f};
        acc[nt][1] = (f32x4){0.f, 0.f, 0.f, 0.f};
    }
    const unsigned short* wb = wbig_l + (size_t)(wave * 8) * 10 * 512;
    #pragma unroll
    for (int ks = 0; ks < 10; ++ks) {
        bf16x8 a0, a1;
        const int koff = ks * 32 + q * 8;
        if (ks < 4) {
            a0 = *(const bf16x8*)(hbf + (size_t)src0 * CD + koff);
            a1 = *(const bf16x8*)(hbf + (size_t)src1 * CD + koff);
        } else if (ks < 8) {
            a0 = *(const bf16x8*)(hbf + (size_t)dst0 * CD + (koff - 128));
            a1 = *(const bf16x8*)(hbf + (size_t)dst1 * CD + (koff - 128));
        } else {
            a0 = *(const bf16x8*)&s_s[e0][koff - 256];
            a1 = *(const bf16x8*)&s_s[e1][koff - 256];
        }
        #pragma unroll
        for (int nt = 0; nt < 8; ++nt) {
            bf16x8 b = *(const bf16x8*)(wb + (size_t)(nt * 10 + ks) * 512 + lane * 8);
            acc[nt][0] = __builtin_amdgcn_mfma_f32_16x16x32_bf16(a0, b, acc[nt][0], 0, 0, 0);
            acc[nt][1] = __builtin_amdgcn_mfma_f32_16x16x32_bf16(a1, b, acc[nt][1], 0, 0, 0);
        }
    }
    // epilogue: + cep, silu, bf16 -> s_t
    #pragma unroll
    for (int nt = 0; nt < 8; ++nt) {
        const int col = wave * 128 + nt * 16 + m;
        const float c = cep_l[col];
        #pragma unroll
        for (int mt = 0; mt < 2; ++mt) {
            #pragma unroll
            for (int i = 0; i < 4; ++i) {
                float tv = silu_f(acc[nt][mt][i] + c);
                s_t[mt * 16 + q * 4 + i][col] = f2bf(tv);
            }
        }
    }
    __syncthreads();

    // ---- GEMM2 ----
    f32x4 acc2[2][2];
    #pragma unroll
    for (int nt = 0; nt < 2; ++nt) {
        acc2[nt][0] = (f32x4){0.f, 0.f, 0.f, 0.f};
        acc2[nt][1] = (f32x4){0.f, 0.f, 0.f, 0.f};
    }
    #pragma unroll
    for (int ks = 0; ks < 8; ++ks) {
        bf16x8 a0 = *(const bf16x8*)&s_t[e0][ks * 32 + q * 8];
        bf16x8 a1 = *(const bf16x8*)&s_t[e1][ks * 32 + q * 8];
        #pragma unroll
        for (int nt = 0; nt < 2; ++nt) {
            bf16x8 b = *(const bf16x8*)(wn2_l + (size_t)((wave * 2 + nt) * 8 + ks) * 512 + lane * 8);
            acc2[nt][0] = __builtin_amdgcn_mfma_f32_16x16x32_bf16(a0, b, acc2[nt][0], 0, 0, 0);
            acc2[nt][1] = __builtin_amdgcn_mfma_f32_16x16x32_bf16(a1, b, acc2[nt][1], 0, 0, 0);
        }
    }
    #pragma unroll
    for (int nt = 0; nt < 2; ++nt) {
        const int col = wave * 32 + nt * 16 + m;
        const float bb = bn2l[col];
        #pragma unroll
        for (int mt = 0; mt < 2; ++mt) {
            #pragma unroll
            for (int i = 0; i < 4; ++i) {
                const int e = mt * 16 + q * 4 + i;
                atomicAdd(&h_out[(size_t)s_dst[e] * CD + col], acc2[nt][mt][i] + bb);
            }
        }
    }

    // ---- coord path ----
    {
        const int e = tid >> 3, r = tid & 7;
        float sum = 0.f;
        #pragma unroll 8
        for (int k = r; k < 256; k += 8)
            sum += bf2f(s_t[e][256 + k]) * s_wc2[k];
        sum += __shfl_xor(sum, 1);
        sum += __shfl_xor(sum, 2);
        sum += __shfl_xor(sum, 4);
        if (r == 0) {
            const int sn = s_src[e], dn = s_dst[e];
            float dx0 = x_in[sn * 3 + 0] - x_in[dn * 3 + 0];
            float dx1 = x_in[sn * 3 + 1] - x_in[dn * 3 + 1];
            float dx2 = x_in[sn * 3 + 2] - x_in[dn * 3 + 2];
            atomicAdd(&x_out[dn * 3 + 0], sum * dx0);
            atomicAdd(&x_out[dn * 3 + 1], sum * dx1);
            atomicAdd(&x_out[dn * 3 + 2], sum * dx2);
        }
    }
}

// ---------------------------------------------------------------------------
// Final LayerNorm over C=128 + copy x.
// ---------------------------------------------------------------------------
__global__ __launch_bounds__(256) void final_kernel(
        const float* __restrict__ h, const float* __restrict__ x,
        const float* __restrict__ gamma, const float* __restrict__ beta,
        float* __restrict__ out)
{
    const int lane = threadIdx.x & 63;
    const int wave = threadIdx.x >> 6;
    const int n = blockIdx.x * 4 + wave;
    float v0 = h[(size_t)n * CD + lane];
    float v1 = h[(size_t)n * CD + 64 + lane];
    float ssum = v0 + v1;
    for (int off = 32; off; off >>= 1) ssum += __shfl_xor(ssum, off);
    float mu = ssum * (1.f / 128.f);
    float d0 = v0 - mu, d1 = v1 - mu;
    float sq = d0 * d0 + d1 * d1;
    for (int off = 32; off; off >>= 1) sq += __shfl_xor(sq, off);
    float rstd = rsqrtf(sq * (1.f / 128.f) + 1e-5f);
    out[(size_t)n * CD + lane]      = gamma[lane]      * d0 * rstd + beta[lane];
    out[(size_t)n * CD + 64 + lane] = gamma[64 + lane] * d1 * rstd + beta[64 + lane];
    if (threadIdx.x < 12) {
        int nn = blockIdx.x * 4 + threadIdx.x / 3;
        int c = threadIdx.x % 3;
        out[(size_t)NN * CD + nn * 3 + c] = x[nn * 3 + c];
    }
}

static inline size_t align_up(size_t v) { return (v + 255) & ~(size_t)255; }

extern "C" void kernel_launch(void* const* d_in, const int* in_sizes, int n_in,
                              void* d_out, int out_size, void* d_ws, size_t ws_size,
                              hipStream_t stream)
{
    const float* single = (const float*)d_in[0];
    const float* coords = (const float*)d_in[2];
    const int*   eidx   = (const int*)d_in[3];
    const float* edist  = (const float*)d_in[4];
    const float* We1 = (const float*)d_in[5];
    const float* be1 = (const float*)d_in[6];
    const float* We2 = (const float*)d_in[7];
    const float* be2 = (const float*)d_in[8];
    const float* Wn1 = (const float*)d_in[9];
    const float* bn1 = (const float*)d_in[10];
    const float* Wn2 = (const float*)d_in[11];
    const float* bn2 = (const float*)d_in[12];
    const float* Wc1 = (const float*)d_in[13];
    const float* bc1 = (const float*)d_in[14];
    const float* Wc2 = (const float*)d_in[15];
    const float* gamma = (const float*)d_in[16];
    const float* beta  = (const float*)d_in[17];
    float* out = (float*)d_out;

    char* w = (char*)d_ws;
    float* h0  = (float*)w;  w += align_up((size_t)NN * CD * 4);
    float* h1  = (float*)w;  w += align_up((size_t)NN * CD * 4);
    float* x0  = (float*)w;  w += align_up((size_t)NN * 3 * 4);
    float* x1  = (float*)w;  w += align_up((size_t)NN * 3 * 4);
    unsigned short* hbf  = (unsigned short*)w; w += align_up((size_t)NN * CD * 2);
    unsigned short* wbig = (unsigned short*)w; w += align_up((size_t)4 * 512 * 320 * 2);
    unsigned short* wn2s = (unsigned short*)w; w += align_up((size_t)4 * 256 * 128 * 2);
    float* cep = (float*)w;  w += align_up((size_t)4 * 512 * 4);

    wbig_prep<<<dim3(320, 4), 64, 0, stream>>>(We2, Wn1, Wc1, wbig);
    wn2_prep<<<dim3(64, 4), 64, 0, stream>>>(Wn2, wn2s);
    cep_prep<<<4, 512, 0, stream>>>(be2, Wn1, Wc1, bn1, bc1, cep);

    hipMemcpyAsync(h0, single, (size_t)NN * CD * 4, hipMemcpyDeviceToDevice, stream);
    hipMemcpyAsync(x0, coords, (size_t)NN * 3 * 4, hipMemcpyDeviceToDevice, stream);
    conv_kernel<<<(NN * CD) / 1024, 256, 0, stream>>>(single, hbf);

    float* hc = h0; float* hn = h1; float* xc = x0; float* xn = x1;
    for (int l = 0; l < 4; ++l) {
        hipMemcpyAsync(hn, hc, (size_t)NN * CD * 4, hipMemcpyDeviceToDevice, stream);
        hipMemcpyAsync(xn, xc, (size_t)NN * 3 * 4, hipMemcpyDeviceToDevice, stream);
        edge_kernel<<<NE / EPB, 256, 0, stream>>>(
            eidx, edist,
            We1 + l * 64, be1 + l * 64,
            hbf,
            wbig + (size_t)l * 512 * 320,
            wn2s + (size_t)l * 256 * 128,
            cep + l * 512, bn2 + l * CD, Wc2 + l * 256,
            xc, hn, xn);
        if (l < 3)
            conv_kernel<<<(NN * CD) / 1024, 256, 0, stream>>>(hn, hbf);
        float* t;
        t = hc; hc = hn; hn = t;
        t = xc; xc = xn; xn = t;
    }
    final_kernel<<<NN / 4, 256, 0, stream>>>(hc, xc, gamma, beta, out);
}